// Round 11
// baseline (21.170 us; speedup 1.0000x reference)
//
#include <hip/hip_runtime.h>

// NodeCycleFeatures via MFMA, 4 waves/block, TWO batches per block interleaved.
// B=2048, N=64, A = E[...,1] symmetric 0/1, zero diag.
// Wave w owns MFMA tile (R,C)=(w>>1,w&1) of k2=A@A and k3=k2@A for BOTH
// batches (v_mfma_f32_32x32x16_bf16; all values integer-exact).
// C/D layout (verified R8-R10): col=lane&31, row=(reg&3)+8*(reg>>2)+4*(lane>>5).
// k2/k3 stored col-major (== row-major by symmetry), 16B-block XOR swizzle.
// Interleaving two independent batches fills every stall (global latency,
// ds_read latency, MFMA deps, barrier drains) with the other batch's stream.

typedef __attribute__((ext_vector_type(8))) short bf16x8;
typedef __attribute__((ext_vector_type(16))) float f32x16;

constexpr int BATCH = 2048;
constexpr int NN = 64;

__device__ __forceinline__ bf16x8 frag_ld(const unsigned short* buf, int row, int kb2) {
  const int idx = row * 64 + ((kb2 ^ (row & 7)) << 3);  // 16B-block swizzle
  const uint4 v = *reinterpret_cast<const uint4*>(buf + idx);
  union { uint4 u; bf16x8 b; } cv; cv.u = v; return cv.b;
}

__device__ __forceinline__ void build_masks(const float4* __restrict__ Eb,
                                            int w, int lane, int h,
                                            unsigned short (*slw)[64]) {
  unsigned mA = 0u, mB = 0u;
  #pragma unroll
  for (int q = 0; q < 8; ++q) {
    const float4 f = Eb[w * 512 + q * 64 + lane];  // row=16w+2q+h, colpair=lane&31
    const int bit = 2 * q + h;
    mA |= (unsigned)(f.y > 0.5f) << bit;
    mB |= (unsigned)(f.w > 0.5f) << bit;
  }
  mA |= (unsigned)__shfl_xor((int)mA, 32);
  mB |= (unsigned)__shfl_xor((int)mB, 32);
  if (lane < 32) {
    slw[w][2 * lane]     = (unsigned short)mA;
    slw[w][2 * lane + 1] = (unsigned short)mB;
  }
}

__device__ __forceinline__ void write_A(unsigned short* bA, uint2 mm, int w, int lane) {
  const unsigned word = (w < 2) ? mm.x : mm.y;
  const unsigned bits16 = (word >> (16 * (w & 1))) & 0xffffu;
  #pragma unroll
  for (int e = 0; e < 2; ++e) {
    const int bq = 2 * w + e;
    unsigned wv[4];
    #pragma unroll
    for (int p2 = 0; p2 < 4; ++p2) {
      const int c0 = e * 8 + p2 * 2;
      wv[p2] = (((bits16 >> c0) & 1u) ? 0x3F80u : 0u)
             | (((bits16 >> (c0 + 1)) & 1u) ? 0x3F800000u : 0u);
    }
    const int idx = lane * 64 + ((bq ^ (lane & 7)) << 3);
    *reinterpret_cast<uint4*>(&bA[idx]) = make_uint4(wv[0], wv[1], wv[2], wv[3]);
  }
}

__device__ __forceinline__ f32x16 do_mm(const unsigned short* bufOp, const bf16x8* Bf,
                                        int R, int c31, int h) {
  f32x16 acc;
  #pragma unroll
  for (int r = 0; r < 16; ++r) acc[r] = 0.f;
  #pragma unroll
  for (int K = 0; K < 4; ++K) {
    const bf16x8 af = frag_ld(bufOp, R * 32 + c31, 2 * K + h);
    acc = __builtin_amdgcn_mfma_f32_32x32x16_bf16(af, Bf[K], acc, 0, 0, 0);
  }
  return acc;
}

__device__ __forceinline__ void pack_k2(unsigned short* bK2, const f32x16& acc,
                                        int R, int C, int c31, int h) {
  const int c = C * 32 + c31;
  #pragma unroll
  for (int g = 0; g < 4; ++g) {
    const unsigned w0 = (__float_as_uint(acc[4*g+1]) & 0xffff0000u) |
                        (__float_as_uint(acc[4*g+0]) >> 16);
    const unsigned w1 = (__float_as_uint(acc[4*g+3]) & 0xffff0000u) |
                        (__float_as_uint(acc[4*g+2]) >> 16);
    const int bb = (4 * R + g) ^ (c & 7);
    *reinterpret_cast<uint2*>(&bK2[c * 64 + bb * 8 + h * 4]) = make_uint2(w0, w1);
  }
}

__device__ __forceinline__ void pack_k3(unsigned short* bK3, const f32x16& d,
                                        int R, int C, int c31, int h) {
  const int c = C * 32 + c31;
  #pragma unroll
  for (int g = 0; g < 4; ++g) {
    const unsigned u0 = ((unsigned)d[4*g+0]) | (((unsigned)d[4*g+1]) << 16);
    const unsigned u1 = ((unsigned)d[4*g+2]) | (((unsigned)d[4*g+3]) << 16);
    const int bb = (4 * R + g) ^ (c & 7);
    *reinterpret_cast<uint2*>(&bK3[c * 64 + bb * 8 + h * 4]) = make_uint2(u0, u1);
  }
}

__device__ __forceinline__ void diag_c3(float* c3p, const f32x16& d,
                                        int R, int C, int c31, int h) {
  if (R == C) {
    const int dtarget = c31 - 4 * h;
    float c3d = 0.f;
    #pragma unroll
    for (int r = 0; r < 16; ++r) {
      const int rowbase = (r & 3) + 8 * (r >> 2);
      c3d += (rowbase == dtarget) ? d[r] : 0.f;
    }
    if (((c31 >> 2) & 1) == h) c3p[R * 32 + c31] = c3d;
  }
}

struct RP { float diag4, Ad, diag5, t3p, Atri, t1p, t8p; };

__device__ __forceinline__ RP rowpass(const unsigned short* bK2, const unsigned short* bK3,
                                      const float* c3p, uint2 mr, int rp_r, int rp_q) {
  RP o = {0.f, 0.f, 0.f, 0.f, 0.f, 0.f, 0.f};
  #pragma unroll
  for (int e = 0; e < 2; ++e) {
    const int bq = 2 * rp_q + e;
    const int idx = rp_r * 64 + ((bq ^ (rp_r & 7)) << 3);
    const uint4 vk2 = *reinterpret_cast<const uint4*>(&bK2[idx]);
    const uint4 vk3 = *reinterpret_cast<const uint4*>(&bK3[idx]);
    const float4 c3a = *reinterpret_cast<const float4*>(&c3p[bq * 8]);
    const float4 c3b = *reinterpret_cast<const float4*>(&c3p[bq * 8 + 4]);
    const unsigned wk2[4] = {vk2.x, vk2.y, vk2.z, vk2.w};
    const unsigned wk3[4] = {vk3.x, vk3.y, vk3.z, vk3.w};
    const float c3v[8] = {c3a.x, c3a.y, c3a.z, c3a.w, c3b.x, c3b.y, c3b.z, c3b.w};
    #pragma unroll
    for (int e2 = 0; e2 < 4; ++e2) {
      const int j0 = bq * 8 + 2 * e2;
      const float k2lo = __uint_as_float(wk2[e2] << 16);
      const float k2hi = __uint_as_float(wk2[e2] & 0xffff0000u);
      const float k3lo = (float)(wk3[e2] & 0xffffu);
      const float k3hi = (float)(wk3[e2] >> 16);
      o.diag4 = fmaf(k2lo, k2lo, fmaf(k2hi, k2hi, o.diag4));
      o.Ad += k2lo + k2hi;                             // (A@d)[r] = row-sum of k2
      o.diag5 = fmaf(k2lo, k3lo, fmaf(k2hi, k3hi, o.diag5));
      o.t1p = fmaf(k3lo, k3lo, fmaf(k3hi, k3hi, o.t1p)); // -> trace(k6)
      o.t8p += k3lo + k3hi;                              // -> sum(k3)
      const unsigned b0 = (j0 < 32 ? (mr.x >> j0) : (mr.y >> (j0 - 32))) & 1u;
      const unsigned b1 = ((j0 + 1) < 32 ? (mr.x >> (j0 + 1)) : (mr.y >> (j0 + 1 - 32))) & 1u;
      o.t3p = fmaf(b0 ? k2lo : 0.f, k2lo, fmaf(b1 ? k2hi : 0.f, k2hi, o.t3p));
      o.Atri += (b0 ? c3v[2 * e2] : 0.f) + (b1 ? c3v[2 * e2 + 1] : 0.f);
    }
  }
  return o;
}

__device__ __forceinline__ void epilogue(const RP& r, uint2 mr, float c3i, float m_r,
                                         int bb, int rp_r, int rp_q, int lane, int w,
                                         float* __restrict__ out, float4* gp) {
  const float di = (float)(__popc(mr.x) + __popc(mr.y));
  const float c4 = r.diag4 - di * (di - 1.f) - r.Ad;
  const float c5 = r.diag5 - 2.f * c3i * di - r.Atri + c3i;
  const float c6p = r.t1p + 3.f * r.t8p
            - 3.f * (c3i * c3i)
            + 9.f * r.t3p
            - 6.f * (di * r.diag4)
            + 6.f * r.diag4
            - 4.f * c3i
            + 4.f * (di * di * di)
            - 12.f * (di * di)
            + 4.f * di;

  if (rp_q == 0) {
    float* xo = out + ((size_t)bb * NN + rp_r) * 3;
    xo[0] = fminf(c3i * 0.05f * m_r, 1.f);
    xo[1] = fminf(c4  * 0.05f * m_r, 1.f);
    xo[2] = fminf(c5  * 0.05f * m_r, 1.f);
  }

  float sc3 = c3i, sc4 = c4, sc5 = c5, sc6 = c6p;
  #pragma unroll
  for (int off = 4; off < 64; off <<= 1) {   // lanes l,l+4,... = 16 distinct rows
    sc3 += __shfl_xor(sc3, off);
    sc4 += __shfl_xor(sc4, off);
    sc5 += __shfl_xor(sc5, off);
    sc6 += __shfl_xor(sc6, off);
  }
  if (lane == 0) gp[w] = make_float4(sc3, sc4, sc5, sc6);
}

__global__ __launch_bounds__(256, 4) void node_cycle_kernel(
    const float4* __restrict__ E4,   // [B,N,N,2] floats viewed as float4
    const float* __restrict__ nmask, // [B,N]
    float* __restrict__ out)         // x: [B,N,3] then y: [B,4]
{
  const int tid = threadIdx.x;
  const int lane = tid & 63;
  const int w = tid >> 6;            // wave id 0..3
  const int h = lane >> 5;           // lane half (MFMA k-half)
  const int c31 = lane & 31;
  const int R = w >> 1, C = w & 1;   // this wave's MFMA tile
  const int b0 = blockIdx.x * 2;     // two batches per block

  __shared__ unsigned short bufA[2][4096];   // A bf16; reused for k3 (u16)
  __shared__ unsigned short bufK2[2][4096];  // k2 bf16
  __shared__ unsigned short sl[2][4][64];    // 16-bit col-mask slices
  __shared__ uint2 rms[2][NN];               // full row masks
  __shared__ float c3sh[2][NN];
  __shared__ float4 gpart[2][4];

  const float4* __restrict__ Eb0 = E4 + (size_t)b0 * 2048;
  const float4* __restrict__ Eb1 = Eb0 + 2048;

  const int rp_r = 16 * w + (lane >> 2);     // row-pass: 4 lanes per row
  const int rp_q = lane & 3;
  const float m_r0 = nmask[(size_t)b0 * NN + rp_r];
  const float m_r1 = nmask[(size_t)(b0 + 1) * NN + rp_r];

  // ---- Phase L: masks for both batches ----
  build_masks(Eb0, w, lane, h, sl[0]);
  build_masks(Eb1, w, lane, h, sl[1]);
  __syncthreads();                                    // B1

  // ---- Assemble full row masks: 256 threads cover 2 batches x 64 x 2 halves ----
  {
    const int bi = tid >> 7;
    const int t = tid & 127;
    const int c = t >> 1, hf = t & 1;
    const unsigned v = (unsigned)sl[bi][2 * hf][c] | ((unsigned)sl[bi][2 * hf + 1][c] << 16);
    if (hf == 0) rms[bi][c].x = v; else rms[bi][c].y = v;
  }
  __syncthreads();                                    // B2

  write_A(bufA[0], rms[0][lane], w, lane);
  write_A(bufA[1], rms[1][lane], w, lane);
  __syncthreads();                                    // B3

  // ---- m1 both batches ----
  bf16x8 Bf0[4], Bf1[4];
  #pragma unroll
  for (int K = 0; K < 4; ++K) {
    Bf0[K] = frag_ld(bufA[0], C * 32 + c31, 2 * K + h);
    Bf1[K] = frag_ld(bufA[1], C * 32 + c31, 2 * K + h);
  }
  const f32x16 acc0 = do_mm(bufA[0], Bf0, R, c31, h);
  const f32x16 acc1 = do_mm(bufA[1], Bf1, R, c31, h);
  pack_k2(bufK2[0], acc0, R, C, c31, h);
  pack_k2(bufK2[1], acc1, R, C, c31, h);
  __syncthreads();                                    // B4

  // ---- m2 both batches ----
  const f32x16 d0 = do_mm(bufK2[0], Bf0, R, c31, h);
  const f32x16 d1 = do_mm(bufK2[1], Bf1, R, c31, h);
  diag_c3(c3sh[0], d0, R, C, c31, h);
  diag_c3(c3sh[1], d1, R, C, c31, h);
  pack_k3(bufA[0], d0, R, C, c31, h);
  pack_k3(bufA[1], d1, R, C, c31, h);
  __syncthreads();                                    // B5

  // ---- Row-pass both batches + 2-level quarter-lane butterfly ----
  const uint2 mr0 = rms[0][rp_r];
  const uint2 mr1 = rms[1][rp_r];
  RP r0 = rowpass(bufK2[0], bufA[0], c3sh[0], mr0, rp_r, rp_q);
  RP r1 = rowpass(bufK2[1], bufA[1], c3sh[1], mr1, rp_r, rp_q);
  #pragma unroll
  for (int off = 1; off <= 2; off <<= 1) {
    r0.diag4 += __shfl_xor(r0.diag4, off); r1.diag4 += __shfl_xor(r1.diag4, off);
    r0.Ad    += __shfl_xor(r0.Ad, off);    r1.Ad    += __shfl_xor(r1.Ad, off);
    r0.diag5 += __shfl_xor(r0.diag5, off); r1.diag5 += __shfl_xor(r1.diag5, off);
    r0.t3p   += __shfl_xor(r0.t3p, off);   r1.t3p   += __shfl_xor(r1.t3p, off);
    r0.Atri  += __shfl_xor(r0.Atri, off);  r1.Atri  += __shfl_xor(r1.Atri, off);
    r0.t1p   += __shfl_xor(r0.t1p, off);   r1.t1p   += __shfl_xor(r1.t1p, off);
    r0.t8p   += __shfl_xor(r0.t8p, off);   r1.t8p   += __shfl_xor(r1.t8p, off);
  }

  epilogue(r0, mr0, c3sh[0][rp_r], m_r0, b0,     rp_r, rp_q, lane, w, out, gpart[0]);
  epilogue(r1, mr1, c3sh[1][rp_r], m_r1, b0 + 1, rp_r, rp_q, lane, w, out, gpart[1]);
  __syncthreads();                                    // B6

  if (tid < 2) {
    const float4 g0 = gpart[tid][0], g1 = gpart[tid][1],
                 g2 = gpart[tid][2], g3 = gpart[tid][3];
    float4 y;
    y.x = fminf((g0.x + g1.x + g2.x + g3.x) * (1.f / 6.f)  * 0.1f, 1.f);
    y.y = fminf((g0.y + g1.y + g2.y + g3.y) * (1.f / 8.f)  * 0.1f, 1.f);
    y.z = fminf((g0.z + g1.z + g2.z + g3.z) * (1.f / 10.f) * 0.1f, 1.f);
    y.w = fminf((g0.w + g1.w + g2.w + g3.w) * (1.f / 12.f) * 0.1f, 1.f);
    *reinterpret_cast<float4*>(out + (size_t)BATCH * NN * 3 + (b0 + tid) * 4) = y;
  }
}

extern "C" void kernel_launch(void* const* d_in, const int* in_sizes, int n_in,
                              void* d_out, int out_size, void* d_ws, size_t ws_size,
                              hipStream_t stream) {
  const float4* E4 = reinterpret_cast<const float4*>(d_in[0]);
  const float* nmask = reinterpret_cast<const float*>(d_in[1]);
  float* out = reinterpret_cast<float*>(d_out);
  node_cycle_kernel<<<BATCH / 2, 256, 0, stream>>>(E4, nmask, out);
}